// Round 21
// baseline (251.668 us; speedup 1.0000x reference)
//
#include <hip/hip_runtime.h>
#include <hip/hip_bf16.h>

typedef __bf16 bf16;
typedef __bf16 bf16x8 __attribute__((ext_vector_type(8)));
typedef __bf16 bf16x4 __attribute__((ext_vector_type(4)));
typedef float f32x4 __attribute__((ext_vector_type(4)));

// ---------------------------------------------------------------------------
// Shapes: H=8, CH=32, S=256, NR=256, C=128, M = NR*S = 65536
// Fragment facts (validated R2..R20 passes):
//   mfma_f32_16x16x32_bf16: A row=lane&15,k=8g+i ; B col=lane&15,k=8g+i ;
//                           D col=lane&15, row=4g+j   (learn_hip m89)
// Structure = R19 (best: 184.2 us). R20 lesson: doubling attn LDS for
// double-buffering dropped residency to 1 block/CU -> regression; cross-
// block TLP is the latency hider here. R21 delta: attn LDS trimmed to
// exactly 32 KB (bms read direct from L2) -> 5 blocks/CU, LB(256,5).
// perm(ch) = ((ch>>2)&3)*8 + ((ch>>4)&1)*4 + (ch&3)   (G/Og channel order)
// K image:  elem (t,ch) at t*32 + (((ch>>3) ^ ((t>>1)&3))<<3) + (ch&7)
// V image:  elem (ch,t) at ((t>>2)*32 + (ch ^ ((t>>2)&7)))*4 + (t&3)
// ---------------------------------------------------------------------------

#define M_TOT 65536
#define LOG2E 1.4426950408889634f

static __device__ __forceinline__ f32x4 mfma32(bf16x8 a, bf16x8 b, f32x4 c) {
    return __builtin_amdgcn_mfma_f32_16x16x32_bf16(a, b, c, 0, 0, 0);
}

static __device__ __forceinline__ float exp2_(float x) {
#if __has_builtin(__builtin_amdgcn_exp2f)
    return __builtin_amdgcn_exp2f(x);
#else
    return exp2f(x);
#endif
}

// async 16B/lane global->LDS: lds dest = uniform base + lane*16 (HW rule)
static __device__ __forceinline__ void g2lds16(bf16* lds_base, const bf16* g_lane) {
#if __has_builtin(__builtin_amdgcn_global_load_lds)
    __builtin_amdgcn_global_load_lds(
        (const __attribute__((address_space(1))) void*)g_lane,
        (__attribute__((address_space(3))) void*)lds_base, 16, 0, 0);
#else
    int lane = threadIdx.x & 63;
    *(bf16x8*)(lds_base + lane * 8) = *(const bf16x8*)g_lane;
#endif
}

static __device__ __forceinline__ int permch(int ch) {
    return ((ch >> 2) & 3) * 8 + ((ch >> 4) & 1) * 4 + (ch & 3);
}

// ---------------- prep: weight transposes + scaled biases ------------------
__global__ void wprep_kernel(const float* __restrict__ wq, const float* __restrict__ wk,
                             const float* __restrict__ wv, const float* __restrict__ wg,
                             const float* __restrict__ wo, bf16* __restrict__ Wt,
                             const float* __restrict__ bp, bf16* __restrict__ bpb,
                             const float* __restrict__ bm, float* __restrict__ bms)
{
    int job = blockIdx.y;
    int idx = blockIdx.x * 256 + threadIdx.x;   // 0..32767 (grid.x = 128)
    if (job == 5) {
        for (int i = idx; i < 8 * 256 * 256; i += 32768)
            bpb[i] = (bf16)(bp[i] * LOG2E);
        return;
    }
    if (job == 6) {
        for (int i = idx; i < 65536; i += 32768)
            bms[i] = bm[i] * LOG2E;
        return;
    }
    if (job == 4) {
        // woT with permuted k index (cancels attn's permuted Og layout)
        int n = idx >> 8, k = idx & 255;        // n: out 0..127, k: in 0..255
        int h = k >> 5, ch = k & 31;
        Wt[4 * 32768 + n * 256 + h * 32 + permch(ch)] = (bf16)wo[k * 128 + n];
        return;
    }
    const float* src;
    switch (job) {
        case 0: src = wq; break;
        case 1: src = wk; break;
        case 2: src = wv; break;
        default: src = wg; break;
    }
    bf16* dst = Wt + job * 32768;
    int n = idx >> 7, k = idx & 127;            // K=128, N=256
    dst[idx] = (bf16)src[k * 256 + n];          // dst[n][k] = src[k][n]
}

// ---------------- projection GEMM body (compile-time MODEs) ----------------
// MODE 1: Q (scaled, transposed D) ; MODE 2: G (sigmoid, perm, transposed D)
// MODE 4: K image (transposed D)   ; MODE 3: V image (original D)
// 8 waves: wave w handles m rows [mloc, mloc+64) x n strip [(w&3)*64, +64)
template<int MODE1, int MODE2>
static __device__ __forceinline__
void proj_gemm(bf16 (&Xs)[128][136], int mbase, int tid,
               const bf16* __restrict__ WT1, const float* __restrict__ bias1,
               bf16* __restrict__ O1,
               const bf16* __restrict__ WT2, const float* __restrict__ bias2,
               bf16* __restrict__ O2)
{
    const int lane = tid & 63, w = tid >> 6;
    const int c = lane & 15, g = lane >> 4;
    const int nstrip = (w & 3) * 64;
    const int mloc = (w >> 2) * 64;
    const f32x4 fzero = {0.f, 0.f, 0.f, 0.f};

#pragma unroll
    for (int rep = 0; rep < 2; ++rep) {
        const bf16* WT  = rep ? WT2 : WT1;
        const float* bias = rep ? bias2 : bias1;
        bf16* O = rep ? O2 : O1;
        const int MODE = rep ? MODE2 : MODE1;

        f32x4 acc[4][4];
#pragma unroll
        for (int a = 0; a < 4; ++a)
#pragma unroll
            for (int b = 0; b < 4; ++b) acc[a][b] = fzero;

#pragma unroll
        for (int kk = 0; kk < 4; ++kk) {
            bf16x8 af[4], bfr[4];
#pragma unroll
            for (int mi = 0; mi < 4; ++mi)
                af[mi] = *(const bf16x8*)&Xs[mloc + mi * 16 + c][kk * 32 + g * 8];
#pragma unroll
            for (int ni = 0; ni < 4; ++ni)
                bfr[ni] = *(const bf16x8*)(WT + (size_t)(nstrip + ni * 16 + c) * 128 + kk * 32 + g * 8);
#pragma unroll
            for (int mi = 0; mi < 4; ++mi)
#pragma unroll
                for (int ni = 0; ni < 4; ++ni) {
                    if (MODE == 3)      // V: original (D row=m-local, col=n-local)
                        acc[mi][ni] = mfma32(af[mi], bfr[ni], acc[mi][ni]);
                    else                // Q/G/K: transposed (D row=n-local, col=m-local)
                        acc[mi][ni] = mfma32(bfr[ni], af[mi], acc[mi][ni]);
                }
        }

#pragma unroll
        for (int mi = 0; mi < 4; ++mi)
#pragma unroll
            for (int ni = 0; ni < 4; ++ni) {
                if (MODE == 3) {                     // V image (4 consecutive t)
                    int n = nstrip + ni * 16 + c;
                    int h = n >> 5, ch = n & 31;
                    int m0 = mbase + mloc + mi * 16 + g * 4;
                    int nr = m0 >> 8, t0 = m0 & 255;
                    int tg = t0 >> 2;
                    bf16x4 pk;
#pragma unroll
                    for (int j = 0; j < 4; ++j) pk[j] = (bf16)acc[mi][ni][j];
                    *(bf16x4*)&O[(size_t)(h * 256 + nr) * 8192 + (tg * 32 + (ch ^ (tg & 7))) * 4] = pk;
                } else {
                    // transposed: m fixed per lane, n = nstrip+ni*16+4g+j
                    int m = mbase + mloc + mi * 16 + c;
                    int n0 = nstrip + ni * 16 + 4 * g;     // 4-aligned
                    int h = n0 >> 5, ch0 = n0 & 31;
                    if (MODE == 1) {
                        bf16x4 pk;
#pragma unroll
                        for (int j = 0; j < 4; ++j)
                            pk[j] = (bf16)(acc[mi][ni][j] * 0.2550348652402226f);
                        *(bf16x4*)&O[((size_t)h * M_TOT + (size_t)m) * 32 + ch0] = pk;
                    } else if (MODE == 2) {
                        f32x4 b4 = *(const f32x4*)(bias + n0);
                        bf16x4 pk;
#pragma unroll
                        for (int j = 0; j < 4; ++j)
                            pk[j] = (bf16)(1.f / (1.f + __expf(-(acc[mi][ni][j] + b4[j]))));
                        *(bf16x4*)&O[((size_t)h * M_TOT + (size_t)m) * 32 + permch(ch0)] = pk;
                    } else {                         // MODE 4: K image
                        int nr = m >> 8, t = m & 255;
                        int c4 = ch0 >> 3;
                        bf16x4 pk;
#pragma unroll
                        for (int j = 0; j < 4; ++j) pk[j] = (bf16)acc[mi][ni][j];
                        *(bf16x4*)&O[(size_t)(h * 256 + nr) * 8192 + t * 32 +
                                     ((c4 ^ ((t >> 1) & 3)) << 3) + (ch0 & 7)] = pk;
                    }
                }
            }
    }
}

// ---------------- merged projection launch (template-dispatched) -----------
// grid (512, 2), 512 threads: y=0 -> {Q, G} from q_x ; y=1 -> {K,V imgs}
__global__ __launch_bounds__(512, 2)
void proj_all_kernel(const float* __restrict__ Xq, const float* __restrict__ Xkv,
                     const bf16* __restrict__ Wt, const float* __restrict__ bg,
                     bf16* __restrict__ Q, bf16* __restrict__ G,
                     bf16* __restrict__ Kimg, bf16* __restrict__ Vimg)
{
    __shared__ bf16 Xs[128][136];               // 34.8 KB; +8 pad -> 2-way banks
    const int which = blockIdx.y;               // uniform across block
    const float* X = which ? Xkv : Xq;
    const int tid = threadIdx.x;
    const int mbase = blockIdx.x * 128;

    for (int i = tid; i < 4096; i += 512) {     // 128x128 fp32 -> bf16
        int m = i >> 5;
        int k4 = (i & 31) << 2;
        float4 v = *(const float4*)(X + (size_t)(mbase + m) * 128 + k4);
        bf16x4 pk;
        pk.x = (bf16)v.x; pk.y = (bf16)v.y; pk.z = (bf16)v.z; pk.w = (bf16)v.w;
        *(bf16x4*)&Xs[m][k4] = pk;
    }
    __syncthreads();

    if (which == 0)
        proj_gemm<1, 2>(Xs, mbase, tid, Wt, nullptr, Q, Wt + 3 * 32768, bg, G);
    else
        proj_gemm<4, 3>(Xs, mbase, tid, Wt + 1 * 32768, nullptr, Kimg,
                        Wt + 2 * 32768, nullptr, Vimg);
}

// ---------------- fused attention (R19 structure, 32KB LDS, 5 blocks/CU) ----
// Q: [h][m][32] ; G,Og: [h][m][perm] ; Kimg,Vimg: [h*256+nr][8192]
// bpb: [h][q][t] bf16 (x log2e) ; bms: [nr][t] f32 (x log2e, read from L2)
__global__ __launch_bounds__(256, 5)
void attn_kernel(const bf16* __restrict__ Q, const bf16* __restrict__ Kimg,
                 const bf16* __restrict__ Vimg, const bf16* __restrict__ G,
                 const float* __restrict__ bms, const bf16* __restrict__ bpb,
                 bf16* __restrict__ Og)
{
    __shared__ bf16 Ks[8192];       // 16 KB, K image (already swizzled)
    __shared__ bf16 Vs[8192];       // 16 KB, V image (already swizzled)

    const int h = blockIdx.x, nr = blockIdx.y;
    const int tid = threadIdx.x;
    const int lane = tid & 63, w = tid >> 6;
    const int c = lane & 15, g = lane >> 4;

    // ---- async stage K,V (1KB chunks, 8 in flight per wave) ----------------
    const bf16* Kslab = Kimg + (size_t)(h * 256 + nr) * 8192;
    const bf16* Vslab = Vimg + (size_t)(h * 256 + nr) * 8192;
#pragma unroll
    for (int r = 0; r < 4; ++r) {
        int off = (w * 4 + r) * 512;            // bf16 elems (1KB chunks)
        g2lds16(&Ks[off], Kslab + off + lane * 8);
        g2lds16(&Vs[off], Vslab + off + lane * 8);
    }
    __syncthreads();                            // drains vmcnt (incl. LDS-DMA)

    const bf16* Qh = Q + ((size_t)h * M_TOT + nr * 256) * 32;
    const bf16* Gh = G + ((size_t)h * M_TOT + nr * 256) * 32;
    bf16* Oh = Og + ((size_t)h * M_TOT + nr * 256) * 32;
    const bf16* bph = bpb + (size_t)h * 65536;
    const float* bmr = bms + nr * 256;
    const f32x4 fzero = {0.f, 0.f, 0.f, 0.f};
    const int kswz = (g ^ ((c >> 1) & 3)) << 3; // K read chunk (t-part const)

#pragma unroll
    for (int qc = 0; qc < 4; ++qc) {
        const int q = w * 64 + qc * 16 + c;     // lane-owned token row
        // hoisted loads: Q row, gate (16B, permuted layout), 16 bias vectors
        bf16x8 bq = *(const bf16x8*)(Qh + (size_t)q * 32 + g * 8);
        bf16x8 gv8 = *(const bf16x8*)(Gh + (size_t)q * 32 + g * 8);
        const bf16* bpq = bph + (size_t)q * 256;
        bf16x4 bpv[16];
#pragma unroll
        for (int nt = 0; nt < 16; ++nt)
            bpv[nt] = *(const bf16x4*)(bpq + nt * 16 + 4 * g);

        // QK^T swapped, bias as C operand: s[nt][j] = score*log2e
        f32x4 s[16];
        __builtin_amdgcn_s_setprio(1);
#pragma unroll
        for (int nt = 0; nt < 16; ++nt) {
            f32x4 cin = *(const f32x4*)(bmr + nt * 16 + 4 * g);
#pragma unroll
            for (int j = 0; j < 4; ++j) cin[j] += (float)bpv[nt][j];
            bf16x8 ak = *(const bf16x8*)&Ks[(nt * 16 + c) * 32 + kswz];
            s[nt] = mfma32(ak, bq, cin);
        }
        __builtin_amdgcn_s_setprio(0);

        // exp2 + row sum (4 partial accumulators)
        float rs0 = 0.f, rs1 = 0.f, rs2 = 0.f, rs3 = 0.f;
#pragma unroll
        for (int nt = 0; nt < 16; ++nt) {
            float p0 = exp2_(s[nt][0]), p1 = exp2_(s[nt][1]);
            float p2 = exp2_(s[nt][2]), p3 = exp2_(s[nt][3]);
            s[nt][0] = p0; s[nt][1] = p1; s[nt][2] = p2; s[nt][3] = p3;
            rs0 += p0; rs1 += p1; rs2 += p2; rs3 += p3;
        }
        float rs = (rs0 + rs1) + (rs2 + rs3);
        rs += __shfl_xor(rs, 16);
        rs += __shfl_xor(rs, 32);
        float rinv = 1.f / rs;

        // PV: paired mfma32, P from registers. o[cc]: q=c, ch=cc*16+4g+j
        f32x4 o[2] = {fzero, fzero};
        __builtin_amdgcn_s_setprio(1);
#pragma unroll
        for (int p2 = 0; p2 < 8; ++p2) {
            bf16x8 pb;
#pragma unroll
            for (int j = 0; j < 4; ++j) {
                pb[j]     = (bf16)s[2 * p2][j];
                pb[4 + j] = (bf16)s[2 * p2 + 1][j];
            }
            const int tg0 = 8 * p2 + g;         // t = 32p2 + 4g + j
            const int tg1 = 8 * p2 + 4 + g;     // t = 32p2 + 16 + 4g + j
#pragma unroll
            for (int cc = 0; cc < 2; ++cc) {
                bf16x4 a0 = *(const bf16x4*)&Vs[(tg0 * 32 + ((cc * 16 + c) ^ (tg0 & 7))) * 4];
                bf16x4 a1 = *(const bf16x4*)&Vs[(tg1 * 32 + ((cc * 16 + c) ^ (tg1 & 7))) * 4];
                bf16x8 av = {a0[0], a0[1], a0[2], a0[3], a1[0], a1[1], a1[2], a1[3]};
                o[cc] = mfma32(av, pb, o[cc]);
            }
        }
        __builtin_amdgcn_s_setprio(0);

        // normalize + gate + store: ONE 16B store in permuted layout
        bf16x8 ov8;
#pragma unroll
        for (int cc = 0; cc < 2; ++cc)
#pragma unroll
            for (int j = 0; j < 4; ++j)
                ov8[cc * 4 + j] = (bf16)(o[cc][j] * rinv * (float)gv8[cc * 4 + j]);
        *(bf16x8*)(Oh + (size_t)q * 32 + g * 8) = ov8;
    }
}

// ---------------- output projection (R19 verbatim) --------------------------
// Og: [8][M][perm] bf16 ; woT: [128][256] bf16 (k permuted identically) ;
// out: [M][128] fp32.  Shared k-permutation cancels in the dot product.
__global__ __launch_bounds__(256, 4)
void out_proj_kernel(const bf16* __restrict__ Og, const bf16* __restrict__ woT,
                     const float* __restrict__ bo, float* __restrict__ out)
{
    const int tid = threadIdx.x;
    const int lane = tid & 63, w = tid >> 6;
    const int c = lane & 15, g = lane >> 4;
    const int mbase = blockIdx.x * 64;
    const int mstrip = mbase + (w >> 1) * 32;
    const int nstrip = (w & 1) * 64;
    const f32x4 fzero = {0.f, 0.f, 0.f, 0.f};

    f32x4 acc[2][4];
#pragma unroll
    for (int a = 0; a < 2; ++a)
#pragma unroll
        for (int b = 0; b < 4; ++b) acc[a][b] = fzero;

#pragma unroll
    for (int kk = 0; kk < 8; ++kk) {              // kk = head
        bf16x8 af[2], bfr[4];
#pragma unroll
        for (int mi = 0; mi < 2; ++mi)
            af[mi] = *(const bf16x8*)(Og + ((size_t)kk * M_TOT + mstrip + mi * 16 + c) * 32 + g * 8);
#pragma unroll
        for (int ni = 0; ni < 4; ++ni)
            bfr[ni] = *(const bf16x8*)(woT + (size_t)(nstrip + ni * 16 + c) * 256 + kk * 32 + g * 8);
#pragma unroll
        for (int mi = 0; mi < 2; ++mi)
#pragma unroll
            for (int ni = 0; ni < 4; ++ni)
                acc[mi][ni] = mfma32(af[mi], bfr[ni], acc[mi][ni]);
    }

#pragma unroll
    for (int mi = 0; mi < 2; ++mi)
#pragma unroll
        for (int ni = 0; ni < 4; ++ni) {
            int n = nstrip + ni * 16 + c;
            float bias = bo[n];
#pragma unroll
            for (int j = 0; j < 4; ++j) {
                int m = mstrip + mi * 16 + g * 4 + j;
                out[(size_t)m * 128 + n] = acc[mi][ni][j] + bias;
            }
        }
}

// ---------------------------------------------------------------------------
extern "C" void kernel_launch(void* const* d_in, const int* in_sizes, int n_in,
                              void* d_out, int out_size, void* d_ws, size_t ws_size,
                              hipStream_t stream)
{
    const float* q_x       = (const float*)d_in[0];
    const float* kv_x      = (const float*)d_in[1];
    const float* bias_mask = (const float*)d_in[2];
    const float* bias_pair = (const float*)d_in[3];
    const float* wq        = (const float*)d_in[4];
    const float* wk        = (const float*)d_in[5];
    const float* wv        = (const float*)d_in[6];
    const float* wg        = (const float*)d_in[7];
    const float* bg        = (const float*)d_in[8];
    const float* wo        = (const float*)d_in[9];
    const float* bo        = (const float*)d_in[10];
    float* out = (float*)d_out;

    char* ws = (char*)d_ws;
    const size_t MB = 1024ull * 1024ull;
    bf16*  Qb  = (bf16*)(ws);                    // [8][65536][32]
    bf16*  Kb  = (bf16*)(ws + 32 * MB);          // K images [2048][8192]
    bf16*  Gb  = (bf16*)(ws + 64 * MB);          // [8][65536][perm]
    bf16*  Vtb = (bf16*)(ws + 96 * MB);          // V images [2048][8192]
    bf16*  Ogb = (bf16*)(ws + 128 * MB);         // [8][65536][perm]
    bf16*  Wt  = (bf16*)(ws + 160 * MB);         // 5 x 32768 bf16 (320 KB)
    bf16*  bpb = (bf16*)(ws + 160 * MB + 512 * 1024);    // [8][256][256] bf16
    float* bms = (float*)(ws + 160 * MB + 2560 * 1024);  // [256][256] f32

    wprep_kernel<<<dim3(128, 7), 256, 0, stream>>>(wq, wk, wv, wg, wo, Wt,
                                                   bias_pair, bpb, bias_mask, bms);

    // Q + G + K image + V image in ONE launch (template-specialized paths)
    proj_all_kernel<<<dim3(512, 2), 512, 0, stream>>>(q_x, kv_x, Wt, bg,
                                                      Qb, Gb, Kb, Vtb);

    attn_kernel<<<dim3(8, 256), 256, 0, stream>>>(Qb, Kb, Vtb, Gb, bms, bpb, Ogb);

    out_proj_kernel<<<dim3(1024), 256, 0, stream>>>(Ogb, Wt + 4 * 32768, bo, out);
}

// Round 22
// 207.347 us; speedup vs baseline: 1.2138x; 1.2138x over previous
//
#include <hip/hip_runtime.h>
#include <hip/hip_bf16.h>

typedef __bf16 bf16;
typedef __bf16 bf16x8 __attribute__((ext_vector_type(8)));
typedef __bf16 bf16x4 __attribute__((ext_vector_type(4)));
typedef float f32x4 __attribute__((ext_vector_type(4)));

// ---------------------------------------------------------------------------
// Shapes: H=8, CH=32, S=256, NR=256, C=128, M = NR*S = 65536
// Fragment facts (validated R2..R21 passes):
//   mfma_f32_16x16x32_bf16: A row=lane&15,k=8g+i ; B col=lane&15,k=8g+i ;
//                           D col=lane&15, row=4g+j   (learn_hip m89)
// Structure = R19 (best: 184.2 us) with attn LDS trimmed to exactly 32 KB
// (bms read direct from L2; it's wave-broadcast + L2-resident) while KEEPING
// LB(256,4). R21 lesson: LB(256,5) forced VGPR 48 -> spills (+71 MB FETCH).
// LB's 2nd arg only constrains the register allocator; residency above the
// guarantee comes free from LDS/VGPR headroom (32KB x 5 = 160KB fits).
// perm(ch) = ((ch>>2)&3)*8 + ((ch>>4)&1)*4 + (ch&3)   (G/Og channel order)
// K image:  elem (t,ch) at t*32 + (((ch>>3) ^ ((t>>1)&3))<<3) + (ch&7)
// V image:  elem (ch,t) at ((t>>2)*32 + (ch ^ ((t>>2)&7)))*4 + (t&3)
// ---------------------------------------------------------------------------

#define M_TOT 65536
#define LOG2E 1.4426950408889634f

static __device__ __forceinline__ f32x4 mfma32(bf16x8 a, bf16x8 b, f32x4 c) {
    return __builtin_amdgcn_mfma_f32_16x16x32_bf16(a, b, c, 0, 0, 0);
}

static __device__ __forceinline__ float exp2_(float x) {
#if __has_builtin(__builtin_amdgcn_exp2f)
    return __builtin_amdgcn_exp2f(x);
#else
    return exp2f(x);
#endif
}

// async 16B/lane global->LDS: lds dest = uniform base + lane*16 (HW rule)
static __device__ __forceinline__ void g2lds16(bf16* lds_base, const bf16* g_lane) {
#if __has_builtin(__builtin_amdgcn_global_load_lds)
    __builtin_amdgcn_global_load_lds(
        (const __attribute__((address_space(1))) void*)g_lane,
        (__attribute__((address_space(3))) void*)lds_base, 16, 0, 0);
#else
    int lane = threadIdx.x & 63;
    *(bf16x8*)(lds_base + lane * 8) = *(const bf16x8*)g_lane;
#endif
}

static __device__ __forceinline__ int permch(int ch) {
    return ((ch >> 2) & 3) * 8 + ((ch >> 4) & 1) * 4 + (ch & 3);
}

// ---------------- prep: weight transposes + scaled biases ------------------
__global__ void wprep_kernel(const float* __restrict__ wq, const float* __restrict__ wk,
                             const float* __restrict__ wv, const float* __restrict__ wg,
                             const float* __restrict__ wo, bf16* __restrict__ Wt,
                             const float* __restrict__ bp, bf16* __restrict__ bpb,
                             const float* __restrict__ bm, float* __restrict__ bms)
{
    int job = blockIdx.y;
    int idx = blockIdx.x * 256 + threadIdx.x;   // 0..32767 (grid.x = 128)
    if (job == 5) {
        for (int i = idx; i < 8 * 256 * 256; i += 32768)
            bpb[i] = (bf16)(bp[i] * LOG2E);
        return;
    }
    if (job == 6) {
        for (int i = idx; i < 65536; i += 32768)
            bms[i] = bm[i] * LOG2E;
        return;
    }
    if (job == 4) {
        // woT with permuted k index (cancels attn's permuted Og layout)
        int n = idx >> 8, k = idx & 255;        // n: out 0..127, k: in 0..255
        int h = k >> 5, ch = k & 31;
        Wt[4 * 32768 + n * 256 + h * 32 + permch(ch)] = (bf16)wo[k * 128 + n];
        return;
    }
    const float* src;
    switch (job) {
        case 0: src = wq; break;
        case 1: src = wk; break;
        case 2: src = wv; break;
        default: src = wg; break;
    }
    bf16* dst = Wt + job * 32768;
    int n = idx >> 7, k = idx & 127;            // K=128, N=256
    dst[idx] = (bf16)src[k * 256 + n];          // dst[n][k] = src[k][n]
}

// ---------------- projection GEMM body (compile-time MODEs) ----------------
// MODE 1: Q (scaled, transposed D) ; MODE 2: G (sigmoid, perm, transposed D)
// MODE 4: K image (transposed D)   ; MODE 3: V image (original D)
// 8 waves: wave w handles m rows [mloc, mloc+64) x n strip [(w&3)*64, +64)
template<int MODE1, int MODE2>
static __device__ __forceinline__
void proj_gemm(bf16 (&Xs)[128][136], int mbase, int tid,
               const bf16* __restrict__ WT1, const float* __restrict__ bias1,
               bf16* __restrict__ O1,
               const bf16* __restrict__ WT2, const float* __restrict__ bias2,
               bf16* __restrict__ O2)
{
    const int lane = tid & 63, w = tid >> 6;
    const int c = lane & 15, g = lane >> 4;
    const int nstrip = (w & 3) * 64;
    const int mloc = (w >> 2) * 64;
    const f32x4 fzero = {0.f, 0.f, 0.f, 0.f};

#pragma unroll
    for (int rep = 0; rep < 2; ++rep) {
        const bf16* WT  = rep ? WT2 : WT1;
        const float* bias = rep ? bias2 : bias1;
        bf16* O = rep ? O2 : O1;
        const int MODE = rep ? MODE2 : MODE1;

        f32x4 acc[4][4];
#pragma unroll
        for (int a = 0; a < 4; ++a)
#pragma unroll
            for (int b = 0; b < 4; ++b) acc[a][b] = fzero;

#pragma unroll
        for (int kk = 0; kk < 4; ++kk) {
            bf16x8 af[4], bfr[4];
#pragma unroll
            for (int mi = 0; mi < 4; ++mi)
                af[mi] = *(const bf16x8*)&Xs[mloc + mi * 16 + c][kk * 32 + g * 8];
#pragma unroll
            for (int ni = 0; ni < 4; ++ni)
                bfr[ni] = *(const bf16x8*)(WT + (size_t)(nstrip + ni * 16 + c) * 128 + kk * 32 + g * 8);
#pragma unroll
            for (int mi = 0; mi < 4; ++mi)
#pragma unroll
                for (int ni = 0; ni < 4; ++ni) {
                    if (MODE == 3)      // V: original (D row=m-local, col=n-local)
                        acc[mi][ni] = mfma32(af[mi], bfr[ni], acc[mi][ni]);
                    else                // Q/G/K: transposed (D row=n-local, col=m-local)
                        acc[mi][ni] = mfma32(bfr[ni], af[mi], acc[mi][ni]);
                }
        }

#pragma unroll
        for (int mi = 0; mi < 4; ++mi)
#pragma unroll
            for (int ni = 0; ni < 4; ++ni) {
                if (MODE == 3) {                     // V image (4 consecutive t)
                    int n = nstrip + ni * 16 + c;
                    int h = n >> 5, ch = n & 31;
                    int m0 = mbase + mloc + mi * 16 + g * 4;
                    int nr = m0 >> 8, t0 = m0 & 255;
                    int tg = t0 >> 2;
                    bf16x4 pk;
#pragma unroll
                    for (int j = 0; j < 4; ++j) pk[j] = (bf16)acc[mi][ni][j];
                    *(bf16x4*)&O[(size_t)(h * 256 + nr) * 8192 + (tg * 32 + (ch ^ (tg & 7))) * 4] = pk;
                } else {
                    // transposed: m fixed per lane, n = nstrip+ni*16+4g+j
                    int m = mbase + mloc + mi * 16 + c;
                    int n0 = nstrip + ni * 16 + 4 * g;     // 4-aligned
                    int h = n0 >> 5, ch0 = n0 & 31;
                    if (MODE == 1) {
                        bf16x4 pk;
#pragma unroll
                        for (int j = 0; j < 4; ++j)
                            pk[j] = (bf16)(acc[mi][ni][j] * 0.2550348652402226f);
                        *(bf16x4*)&O[((size_t)h * M_TOT + (size_t)m) * 32 + ch0] = pk;
                    } else if (MODE == 2) {
                        f32x4 b4 = *(const f32x4*)(bias + n0);
                        bf16x4 pk;
#pragma unroll
                        for (int j = 0; j < 4; ++j)
                            pk[j] = (bf16)(1.f / (1.f + __expf(-(acc[mi][ni][j] + b4[j]))));
                        *(bf16x4*)&O[((size_t)h * M_TOT + (size_t)m) * 32 + permch(ch0)] = pk;
                    } else {                         // MODE 4: K image
                        int nr = m >> 8, t = m & 255;
                        int c4 = ch0 >> 3;
                        bf16x4 pk;
#pragma unroll
                        for (int j = 0; j < 4; ++j) pk[j] = (bf16)acc[mi][ni][j];
                        *(bf16x4*)&O[(size_t)(h * 256 + nr) * 8192 + t * 32 +
                                     ((c4 ^ ((t >> 1) & 3)) << 3) + (ch0 & 7)] = pk;
                    }
                }
            }
    }
}

// ---------------- merged projection launch (template-dispatched) -----------
// grid (512, 2), 512 threads: y=0 -> {Q, G} from q_x ; y=1 -> {K,V imgs}
__global__ __launch_bounds__(512, 2)
void proj_all_kernel(const float* __restrict__ Xq, const float* __restrict__ Xkv,
                     const bf16* __restrict__ Wt, const float* __restrict__ bg,
                     bf16* __restrict__ Q, bf16* __restrict__ G,
                     bf16* __restrict__ Kimg, bf16* __restrict__ Vimg)
{
    __shared__ bf16 Xs[128][136];               // 34.8 KB; +8 pad -> 2-way banks
    const int which = blockIdx.y;               // uniform across block
    const float* X = which ? Xkv : Xq;
    const int tid = threadIdx.x;
    const int mbase = blockIdx.x * 128;

    for (int i = tid; i < 4096; i += 512) {     // 128x128 fp32 -> bf16
        int m = i >> 5;
        int k4 = (i & 31) << 2;
        float4 v = *(const float4*)(X + (size_t)(mbase + m) * 128 + k4);
        bf16x4 pk;
        pk.x = (bf16)v.x; pk.y = (bf16)v.y; pk.z = (bf16)v.z; pk.w = (bf16)v.w;
        *(bf16x4*)&Xs[m][k4] = pk;
    }
    __syncthreads();

    if (which == 0)
        proj_gemm<1, 2>(Xs, mbase, tid, Wt, nullptr, Q, Wt + 3 * 32768, bg, G);
    else
        proj_gemm<4, 3>(Xs, mbase, tid, Wt + 1 * 32768, nullptr, Kimg,
                        Wt + 2 * 32768, nullptr, Vimg);
}

// ---------------- fused attention (R19 body, 32KB LDS, LB(256,4)) -----------
// Q: [h][m][32] ; G,Og: [h][m][perm] ; Kimg,Vimg: [h*256+nr][8192]
// bpb: [h][q][t] bf16 (x log2e) ; bms: [nr][t] f32 (x log2e, L2-resident)
__global__ __launch_bounds__(256, 4)
void attn_kernel(const bf16* __restrict__ Q, const bf16* __restrict__ Kimg,
                 const bf16* __restrict__ Vimg, const bf16* __restrict__ G,
                 const float* __restrict__ bms, const bf16* __restrict__ bpb,
                 bf16* __restrict__ Og)
{
    __shared__ bf16 Ks[8192];       // 16 KB, K image (already swizzled)
    __shared__ bf16 Vs[8192];       // 16 KB, V image (already swizzled)
                                    // total exactly 32 KB -> up to 5 blocks/CU

    const int h = blockIdx.x, nr = blockIdx.y;
    const int tid = threadIdx.x;
    const int lane = tid & 63, w = tid >> 6;
    const int c = lane & 15, g = lane >> 4;

    // ---- async stage K,V (1KB chunks, 8 in flight per wave) ----------------
    const bf16* Kslab = Kimg + (size_t)(h * 256 + nr) * 8192;
    const bf16* Vslab = Vimg + (size_t)(h * 256 + nr) * 8192;
#pragma unroll
    for (int r = 0; r < 4; ++r) {
        int off = (w * 4 + r) * 512;            // bf16 elems (1KB chunks)
        g2lds16(&Ks[off], Kslab + off + lane * 8);
        g2lds16(&Vs[off], Vslab + off + lane * 8);
    }
    __syncthreads();                            // drains vmcnt (incl. LDS-DMA)

    const bf16* Qh = Q + ((size_t)h * M_TOT + nr * 256) * 32;
    const bf16* Gh = G + ((size_t)h * M_TOT + nr * 256) * 32;
    bf16* Oh = Og + ((size_t)h * M_TOT + nr * 256) * 32;
    const bf16* bph = bpb + (size_t)h * 65536;
    const float* bmr = bms + nr * 256;
    const f32x4 fzero = {0.f, 0.f, 0.f, 0.f};
    const int kswz = (g ^ ((c >> 1) & 3)) << 3; // K read chunk (t-part const)

#pragma unroll
    for (int qc = 0; qc < 4; ++qc) {
        const int q = w * 64 + qc * 16 + c;     // lane-owned token row
        // hoisted loads: Q row, gate (16B, permuted layout), 16 bias vectors
        bf16x8 bq = *(const bf16x8*)(Qh + (size_t)q * 32 + g * 8);
        bf16x8 gv8 = *(const bf16x8*)(Gh + (size_t)q * 32 + g * 8);
        const bf16* bpq = bph + (size_t)q * 256;
        bf16x4 bpv[16];
#pragma unroll
        for (int nt = 0; nt < 16; ++nt)
            bpv[nt] = *(const bf16x4*)(bpq + nt * 16 + 4 * g);

        // QK^T swapped, bias as C operand: s[nt][j] = score*log2e
        f32x4 s[16];
        __builtin_amdgcn_s_setprio(1);
#pragma unroll
        for (int nt = 0; nt < 16; ++nt) {
            f32x4 cin = *(const f32x4*)(bmr + nt * 16 + 4 * g);
#pragma unroll
            for (int j = 0; j < 4; ++j) cin[j] += (float)bpv[nt][j];
            bf16x8 ak = *(const bf16x8*)&Ks[(nt * 16 + c) * 32 + kswz];
            s[nt] = mfma32(ak, bq, cin);
        }
        __builtin_amdgcn_s_setprio(0);

        // exp2 + row sum (4 partial accumulators)
        float rs0 = 0.f, rs1 = 0.f, rs2 = 0.f, rs3 = 0.f;
#pragma unroll
        for (int nt = 0; nt < 16; ++nt) {
            float p0 = exp2_(s[nt][0]), p1 = exp2_(s[nt][1]);
            float p2 = exp2_(s[nt][2]), p3 = exp2_(s[nt][3]);
            s[nt][0] = p0; s[nt][1] = p1; s[nt][2] = p2; s[nt][3] = p3;
            rs0 += p0; rs1 += p1; rs2 += p2; rs3 += p3;
        }
        float rs = (rs0 + rs1) + (rs2 + rs3);
        rs += __shfl_xor(rs, 16);
        rs += __shfl_xor(rs, 32);
        float rinv = 1.f / rs;

        // PV: paired mfma32, P from registers. o[cc]: q=c, ch=cc*16+4g+j
        f32x4 o[2] = {fzero, fzero};
        __builtin_amdgcn_s_setprio(1);
#pragma unroll
        for (int p2 = 0; p2 < 8; ++p2) {
            bf16x8 pb;
#pragma unroll
            for (int j = 0; j < 4; ++j) {
                pb[j]     = (bf16)s[2 * p2][j];
                pb[4 + j] = (bf16)s[2 * p2 + 1][j];
            }
            const int tg0 = 8 * p2 + g;         // t = 32p2 + 4g + j
            const int tg1 = 8 * p2 + 4 + g;     // t = 32p2 + 16 + 4g + j
#pragma unroll
            for (int cc = 0; cc < 2; ++cc) {
                bf16x4 a0 = *(const bf16x4*)&Vs[(tg0 * 32 + ((cc * 16 + c) ^ (tg0 & 7))) * 4];
                bf16x4 a1 = *(const bf16x4*)&Vs[(tg1 * 32 + ((cc * 16 + c) ^ (tg1 & 7))) * 4];
                bf16x8 av = {a0[0], a0[1], a0[2], a0[3], a1[0], a1[1], a1[2], a1[3]};
                o[cc] = mfma32(av, pb, o[cc]);
            }
        }
        __builtin_amdgcn_s_setprio(0);

        // normalize + gate + store: ONE 16B store in permuted layout
        bf16x8 ov8;
#pragma unroll
        for (int cc = 0; cc < 2; ++cc)
#pragma unroll
            for (int j = 0; j < 4; ++j)
                ov8[cc * 4 + j] = (bf16)(o[cc][j] * rinv * (float)gv8[cc * 4 + j]);
        *(bf16x8*)(Oh + (size_t)q * 32 + g * 8) = ov8;
    }
}

// ---------------- output projection (R19 verbatim) --------------------------
// Og: [8][M][perm] bf16 ; woT: [128][256] bf16 (k permuted identically) ;
// out: [M][128] fp32.  Shared k-permutation cancels in the dot product.
__global__ __launch_bounds__(256, 4)
void out_proj_kernel(const bf16* __restrict__ Og, const bf16* __restrict__ woT,
                     const float* __restrict__ bo, float* __restrict__ out)
{
    const int tid = threadIdx.x;
    const int lane = tid & 63, w = tid >> 6;
    const int c = lane & 15, g = lane >> 4;
    const int mbase = blockIdx.x * 64;
    const int mstrip = mbase + (w >> 1) * 32;
    const int nstrip = (w & 1) * 64;
    const f32x4 fzero = {0.f, 0.f, 0.f, 0.f};

    f32x4 acc[2][4];
#pragma unroll
    for (int a = 0; a < 2; ++a)
#pragma unroll
        for (int b = 0; b < 4; ++b) acc[a][b] = fzero;

#pragma unroll
    for (int kk = 0; kk < 8; ++kk) {              // kk = head
        bf16x8 af[2], bfr[4];
#pragma unroll
        for (int mi = 0; mi < 2; ++mi)
            af[mi] = *(const bf16x8*)(Og + ((size_t)kk * M_TOT + mstrip + mi * 16 + c) * 32 + g * 8);
#pragma unroll
        for (int ni = 0; ni < 4; ++ni)
            bfr[ni] = *(const bf16x8*)(woT + (size_t)(nstrip + ni * 16 + c) * 256 + kk * 32 + g * 8);
#pragma unroll
        for (int mi = 0; mi < 2; ++mi)
#pragma unroll
            for (int ni = 0; ni < 4; ++ni)
                acc[mi][ni] = mfma32(af[mi], bfr[ni], acc[mi][ni]);
    }

#pragma unroll
    for (int mi = 0; mi < 2; ++mi)
#pragma unroll
        for (int ni = 0; ni < 4; ++ni) {
            int n = nstrip + ni * 16 + c;
            float bias = bo[n];
#pragma unroll
            for (int j = 0; j < 4; ++j) {
                int m = mstrip + mi * 16 + g * 4 + j;
                out[(size_t)m * 128 + n] = acc[mi][ni][j] + bias;
            }
        }
}

// ---------------------------------------------------------------------------
extern "C" void kernel_launch(void* const* d_in, const int* in_sizes, int n_in,
                              void* d_out, int out_size, void* d_ws, size_t ws_size,
                              hipStream_t stream)
{
    const float* q_x       = (const float*)d_in[0];
    const float* kv_x      = (const float*)d_in[1];
    const float* bias_mask = (const float*)d_in[2];
    const float* bias_pair = (const float*)d_in[3];
    const float* wq        = (const float*)d_in[4];
    const float* wk        = (const float*)d_in[5];
    const float* wv        = (const float*)d_in[6];
    const float* wg        = (const float*)d_in[7];
    const float* bg        = (const float*)d_in[8];
    const float* wo        = (const float*)d_in[9];
    const float* bo        = (const float*)d_in[10];
    float* out = (float*)d_out;

    char* ws = (char*)d_ws;
    const size_t MB = 1024ull * 1024ull;
    bf16*  Qb  = (bf16*)(ws);                    // [8][65536][32]
    bf16*  Kb  = (bf16*)(ws + 32 * MB);          // K images [2048][8192]
    bf16*  Gb  = (bf16*)(ws + 64 * MB);          // [8][65536][perm]
    bf16*  Vtb = (bf16*)(ws + 96 * MB);          // V images [2048][8192]
    bf16*  Ogb = (bf16*)(ws + 128 * MB);         // [8][65536][perm]
    bf16*  Wt  = (bf16*)(ws + 160 * MB);         // 5 x 32768 bf16 (320 KB)
    bf16*  bpb = (bf16*)(ws + 160 * MB + 512 * 1024);    // [8][256][256] bf16
    float* bms = (float*)(ws + 160 * MB + 2560 * 1024);  // [256][256] f32

    wprep_kernel<<<dim3(128, 7), 256, 0, stream>>>(wq, wk, wv, wg, wo, Wt,
                                                   bias_pair, bpb, bias_mask, bms);

    // Q + G + K image + V image in ONE launch (template-specialized paths)
    proj_all_kernel<<<dim3(512, 2), 512, 0, stream>>>(q_x, kv_x, Wt, bg,
                                                      Qb, Gb, Kb, Vtb);

    attn_kernel<<<dim3(8, 256), 256, 0, stream>>>(Qb, Kb, Vtb, Gb, bms, bpb, Ogb);

    out_proj_kernel<<<dim3(1024), 256, 0, stream>>>(Ogb, Wt + 4 * 32768, bo, out);
}

// Round 23
// 184.182 us; speedup vs baseline: 1.3664x; 1.1258x over previous
//
#include <hip/hip_runtime.h>
#include <hip/hip_bf16.h>

typedef __bf16 bf16;
typedef __bf16 bf16x8 __attribute__((ext_vector_type(8)));
typedef __bf16 bf16x4 __attribute__((ext_vector_type(4)));
typedef float f32x4 __attribute__((ext_vector_type(4)));

// ---------------------------------------------------------------------------
// Shapes: H=8, CH=32, S=256, NR=256, C=128, M = NR*S = 65536
// Fragment facts (validated R2..R22 passes):
//   mfma_f32_16x16x32_bf16: A row=lane&15,k=8g+i ; B col=lane&15,k=8g+i ;
//                           D col=lane&15, row=4g+j   (learn_hip m89)
// This is R19 verbatim — the session-best configuration (184.2 us):
//   - proj_all: ONE launch, template-specialized paths; Q/G/K computed with
//     SWAPPED mfma operands (D row=n-local) -> bf16x4 vector epilogues;
//     V original orientation (t-fastest image). LB(512,2), VGPR 128.
//   - attn: one (h,nr)/block, 4 waves, ONE barrier; K/V staged via
//     global_load_lds from pre-swizzled images; bms in LDS (load-bearing:
//     R22 showed global bms adds L2 latency to the MFMA C-operand path);
//     swapped QK^T, bias as C operand, exp2, paired-mfma32 register PV;
//     setprio around MFMA clusters. LB(256,4), VGPR 64, LDS 33792.
//   - R20/R21/R22 lessons: double-buffer (-TLP), LB(256,5) (spills), and
//     bms-from-L2 (latency) all regress — this config is a local optimum.
// perm(ch) = ((ch>>2)&3)*8 + ((ch>>4)&1)*4 + (ch&3)   (G/Og channel order)
// K image:  elem (t,ch) at t*32 + (((ch>>3) ^ ((t>>1)&3))<<3) + (ch&7)
// V image:  elem (ch,t) at ((t>>2)*32 + (ch ^ ((t>>2)&7)))*4 + (t&3)
// ---------------------------------------------------------------------------

#define M_TOT 65536
#define LOG2E 1.4426950408889634f

static __device__ __forceinline__ f32x4 mfma32(bf16x8 a, bf16x8 b, f32x4 c) {
    return __builtin_amdgcn_mfma_f32_16x16x32_bf16(a, b, c, 0, 0, 0);
}

static __device__ __forceinline__ float exp2_(float x) {
#if __has_builtin(__builtin_amdgcn_exp2f)
    return __builtin_amdgcn_exp2f(x);
#else
    return exp2f(x);
#endif
}

// async 16B/lane global->LDS: lds dest = uniform base + lane*16 (HW rule)
static __device__ __forceinline__ void g2lds16(bf16* lds_base, const bf16* g_lane) {
#if __has_builtin(__builtin_amdgcn_global_load_lds)
    __builtin_amdgcn_global_load_lds(
        (const __attribute__((address_space(1))) void*)g_lane,
        (__attribute__((address_space(3))) void*)lds_base, 16, 0, 0);
#else
    int lane = threadIdx.x & 63;
    *(bf16x8*)(lds_base + lane * 8) = *(const bf16x8*)g_lane;
#endif
}

static __device__ __forceinline__ int permch(int ch) {
    return ((ch >> 2) & 3) * 8 + ((ch >> 4) & 1) * 4 + (ch & 3);
}

// ---------------- prep: weight transposes + scaled biases ------------------
__global__ void wprep_kernel(const float* __restrict__ wq, const float* __restrict__ wk,
                             const float* __restrict__ wv, const float* __restrict__ wg,
                             const float* __restrict__ wo, bf16* __restrict__ Wt,
                             const float* __restrict__ bp, bf16* __restrict__ bpb,
                             const float* __restrict__ bm, float* __restrict__ bms)
{
    int job = blockIdx.y;
    int idx = blockIdx.x * 256 + threadIdx.x;   // 0..32767 (grid.x = 128)
    if (job == 5) {
        for (int i = idx; i < 8 * 256 * 256; i += 32768)
            bpb[i] = (bf16)(bp[i] * LOG2E);
        return;
    }
    if (job == 6) {
        for (int i = idx; i < 65536; i += 32768)
            bms[i] = bm[i] * LOG2E;
        return;
    }
    if (job == 4) {
        // woT with permuted k index (cancels attn's permuted Og layout)
        int n = idx >> 8, k = idx & 255;        // n: out 0..127, k: in 0..255
        int h = k >> 5, ch = k & 31;
        Wt[4 * 32768 + n * 256 + h * 32 + permch(ch)] = (bf16)wo[k * 128 + n];
        return;
    }
    const float* src;
    switch (job) {
        case 0: src = wq; break;
        case 1: src = wk; break;
        case 2: src = wv; break;
        default: src = wg; break;
    }
    bf16* dst = Wt + job * 32768;
    int n = idx >> 7, k = idx & 127;            // K=128, N=256
    dst[idx] = (bf16)src[k * 256 + n];          // dst[n][k] = src[k][n]
}

// ---------------- projection GEMM body (compile-time MODEs) ----------------
// MODE 1: Q (scaled, transposed D) ; MODE 2: G (sigmoid, perm, transposed D)
// MODE 4: K image (transposed D)   ; MODE 3: V image (original D)
// 8 waves: wave w handles m rows [mloc, mloc+64) x n strip [(w&3)*64, +64)
template<int MODE1, int MODE2>
static __device__ __forceinline__
void proj_gemm(bf16 (&Xs)[128][136], int mbase, int tid,
               const bf16* __restrict__ WT1, const float* __restrict__ bias1,
               bf16* __restrict__ O1,
               const bf16* __restrict__ WT2, const float* __restrict__ bias2,
               bf16* __restrict__ O2)
{
    const int lane = tid & 63, w = tid >> 6;
    const int c = lane & 15, g = lane >> 4;
    const int nstrip = (w & 3) * 64;
    const int mloc = (w >> 2) * 64;
    const f32x4 fzero = {0.f, 0.f, 0.f, 0.f};

#pragma unroll
    for (int rep = 0; rep < 2; ++rep) {
        const bf16* WT  = rep ? WT2 : WT1;
        const float* bias = rep ? bias2 : bias1;
        bf16* O = rep ? O2 : O1;
        const int MODE = rep ? MODE2 : MODE1;

        f32x4 acc[4][4];
#pragma unroll
        for (int a = 0; a < 4; ++a)
#pragma unroll
            for (int b = 0; b < 4; ++b) acc[a][b] = fzero;

#pragma unroll
        for (int kk = 0; kk < 4; ++kk) {
            bf16x8 af[4], bfr[4];
#pragma unroll
            for (int mi = 0; mi < 4; ++mi)
                af[mi] = *(const bf16x8*)&Xs[mloc + mi * 16 + c][kk * 32 + g * 8];
#pragma unroll
            for (int ni = 0; ni < 4; ++ni)
                bfr[ni] = *(const bf16x8*)(WT + (size_t)(nstrip + ni * 16 + c) * 128 + kk * 32 + g * 8);
#pragma unroll
            for (int mi = 0; mi < 4; ++mi)
#pragma unroll
                for (int ni = 0; ni < 4; ++ni) {
                    if (MODE == 3)      // V: original (D row=m-local, col=n-local)
                        acc[mi][ni] = mfma32(af[mi], bfr[ni], acc[mi][ni]);
                    else                // Q/G/K: transposed (D row=n-local, col=m-local)
                        acc[mi][ni] = mfma32(bfr[ni], af[mi], acc[mi][ni]);
                }
        }

#pragma unroll
        for (int mi = 0; mi < 4; ++mi)
#pragma unroll
            for (int ni = 0; ni < 4; ++ni) {
                if (MODE == 3) {                     // V image (4 consecutive t)
                    int n = nstrip + ni * 16 + c;
                    int h = n >> 5, ch = n & 31;
                    int m0 = mbase + mloc + mi * 16 + g * 4;
                    int nr = m0 >> 8, t0 = m0 & 255;
                    int tg = t0 >> 2;
                    bf16x4 pk;
#pragma unroll
                    for (int j = 0; j < 4; ++j) pk[j] = (bf16)acc[mi][ni][j];
                    *(bf16x4*)&O[(size_t)(h * 256 + nr) * 8192 + (tg * 32 + (ch ^ (tg & 7))) * 4] = pk;
                } else {
                    // transposed: m fixed per lane, n = nstrip+ni*16+4g+j
                    int m = mbase + mloc + mi * 16 + c;
                    int n0 = nstrip + ni * 16 + 4 * g;     // 4-aligned
                    int h = n0 >> 5, ch0 = n0 & 31;
                    if (MODE == 1) {
                        bf16x4 pk;
#pragma unroll
                        for (int j = 0; j < 4; ++j)
                            pk[j] = (bf16)(acc[mi][ni][j] * 0.2550348652402226f);
                        *(bf16x4*)&O[((size_t)h * M_TOT + (size_t)m) * 32 + ch0] = pk;
                    } else if (MODE == 2) {
                        f32x4 b4 = *(const f32x4*)(bias + n0);
                        bf16x4 pk;
#pragma unroll
                        for (int j = 0; j < 4; ++j)
                            pk[j] = (bf16)(1.f / (1.f + __expf(-(acc[mi][ni][j] + b4[j]))));
                        *(bf16x4*)&O[((size_t)h * M_TOT + (size_t)m) * 32 + permch(ch0)] = pk;
                    } else {                         // MODE 4: K image
                        int nr = m >> 8, t = m & 255;
                        int c4 = ch0 >> 3;
                        bf16x4 pk;
#pragma unroll
                        for (int j = 0; j < 4; ++j) pk[j] = (bf16)acc[mi][ni][j];
                        *(bf16x4*)&O[(size_t)(h * 256 + nr) * 8192 + t * 32 +
                                     ((c4 ^ ((t >> 1) & 3)) << 3) + (ch0 & 7)] = pk;
                    }
                }
            }
    }
}

// ---------------- merged projection launch (template-dispatched) -----------
// grid (512, 2), 512 threads: y=0 -> {Q, G} from q_x ; y=1 -> {K,V imgs}
__global__ __launch_bounds__(512, 2)
void proj_all_kernel(const float* __restrict__ Xq, const float* __restrict__ Xkv,
                     const bf16* __restrict__ Wt, const float* __restrict__ bg,
                     bf16* __restrict__ Q, bf16* __restrict__ G,
                     bf16* __restrict__ Kimg, bf16* __restrict__ Vimg)
{
    __shared__ bf16 Xs[128][136];               // 34.8 KB; +8 pad -> 2-way banks
    const int which = blockIdx.y;               // uniform across block
    const float* X = which ? Xkv : Xq;
    const int tid = threadIdx.x;
    const int mbase = blockIdx.x * 128;

    for (int i = tid; i < 4096; i += 512) {     // 128x128 fp32 -> bf16
        int m = i >> 5;
        int k4 = (i & 31) << 2;
        float4 v = *(const float4*)(X + (size_t)(mbase + m) * 128 + k4);
        bf16x4 pk;
        pk.x = (bf16)v.x; pk.y = (bf16)v.y; pk.z = (bf16)v.z; pk.w = (bf16)v.w;
        *(bf16x4*)&Xs[m][k4] = pk;
    }
    __syncthreads();

    if (which == 0)
        proj_gemm<1, 2>(Xs, mbase, tid, Wt, nullptr, Q, Wt + 3 * 32768, bg, G);
    else
        proj_gemm<4, 3>(Xs, mbase, tid, Wt + 1 * 32768, nullptr, Kimg,
                        Wt + 2 * 32768, nullptr, Vimg);
}

// ---------------- fused attention (R19 verbatim) ----------------------------
// Q: [h][m][32] ; G,Og: [h][m][perm] ; Kimg,Vimg: [h*256+nr][8192]
// bpb: [h][q][t] bf16 (x log2e) ; bms: [nr][t] f32 (x log2e)
__global__ __launch_bounds__(256, 4)
void attn_kernel(const bf16* __restrict__ Q, const bf16* __restrict__ Kimg,
                 const bf16* __restrict__ Vimg, const bf16* __restrict__ G,
                 const float* __restrict__ bms, const bf16* __restrict__ bpb,
                 bf16* __restrict__ Og)
{
    __shared__ bf16 Ks[8192];       // 16 KB, K image (already swizzled)
    __shared__ bf16 Vs[8192];       // 16 KB, V image (already swizzled)
    __shared__ float bms_s[256];    //  1 KB (load-bearing: keeps bias off
                                    //  the MFMA C-operand latency path)

    const int h = blockIdx.x, nr = blockIdx.y;
    const int tid = threadIdx.x;
    const int lane = tid & 63, w = tid >> 6;
    const int c = lane & 15, g = lane >> 4;

    // ---- async stage K,V (1KB chunks, 8 in flight per wave) ----------------
    const bf16* Kslab = Kimg + (size_t)(h * 256 + nr) * 8192;
    const bf16* Vslab = Vimg + (size_t)(h * 256 + nr) * 8192;
#pragma unroll
    for (int r = 0; r < 4; ++r) {
        int off = (w * 4 + r) * 512;            // bf16 elems (1KB chunks)
        g2lds16(&Ks[off], Kslab + off + lane * 8);
        g2lds16(&Vs[off], Vslab + off + lane * 8);
    }
    bms_s[tid] = bms[nr * 256 + tid];
    __syncthreads();                            // drains vmcnt (incl. LDS-DMA)

    const bf16* Qh = Q + ((size_t)h * M_TOT + nr * 256) * 32;
    const bf16* Gh = G + ((size_t)h * M_TOT + nr * 256) * 32;
    bf16* Oh = Og + ((size_t)h * M_TOT + nr * 256) * 32;
    const bf16* bph = bpb + (size_t)h * 65536;
    const f32x4 fzero = {0.f, 0.f, 0.f, 0.f};
    const int kswz = (g ^ ((c >> 1) & 3)) << 3; // K read chunk (t-part const)

#pragma unroll
    for (int qc = 0; qc < 4; ++qc) {
        const int q = w * 64 + qc * 16 + c;     // lane-owned token row
        // hoisted loads: Q row, gate (16B, permuted layout), 16 bias vectors
        bf16x8 bq = *(const bf16x8*)(Qh + (size_t)q * 32 + g * 8);
        bf16x8 gv8 = *(const bf16x8*)(Gh + (size_t)q * 32 + g * 8);
        const bf16* bpq = bph + (size_t)q * 256;
        bf16x4 bpv[16];
#pragma unroll
        for (int nt = 0; nt < 16; ++nt)
            bpv[nt] = *(const bf16x4*)(bpq + nt * 16 + 4 * g);

        // QK^T swapped, bias as C operand: s[nt][j] = score*log2e
        f32x4 s[16];
        __builtin_amdgcn_s_setprio(1);
#pragma unroll
        for (int nt = 0; nt < 16; ++nt) {
            f32x4 cin = *(const f32x4*)&bms_s[nt * 16 + 4 * g];
#pragma unroll
            for (int j = 0; j < 4; ++j) cin[j] += (float)bpv[nt][j];
            bf16x8 ak = *(const bf16x8*)&Ks[(nt * 16 + c) * 32 + kswz];
            s[nt] = mfma32(ak, bq, cin);
        }
        __builtin_amdgcn_s_setprio(0);

        // exp2 + row sum (4 partial accumulators)
        float rs0 = 0.f, rs1 = 0.f, rs2 = 0.f, rs3 = 0.f;
#pragma unroll
        for (int nt = 0; nt < 16; ++nt) {
            float p0 = exp2_(s[nt][0]), p1 = exp2_(s[nt][1]);
            float p2 = exp2_(s[nt][2]), p3 = exp2_(s[nt][3]);
            s[nt][0] = p0; s[nt][1] = p1; s[nt][2] = p2; s[nt][3] = p3;
            rs0 += p0; rs1 += p1; rs2 += p2; rs3 += p3;
        }
        float rs = (rs0 + rs1) + (rs2 + rs3);
        rs += __shfl_xor(rs, 16);
        rs += __shfl_xor(rs, 32);
        float rinv = 1.f / rs;

        // PV: paired mfma32, P from registers. o[cc]: q=c, ch=cc*16+4g+j
        f32x4 o[2] = {fzero, fzero};
        __builtin_amdgcn_s_setprio(1);
#pragma unroll
        for (int p2 = 0; p2 < 8; ++p2) {
            bf16x8 pb;
#pragma unroll
            for (int j = 0; j < 4; ++j) {
                pb[j]     = (bf16)s[2 * p2][j];
                pb[4 + j] = (bf16)s[2 * p2 + 1][j];
            }
            const int tg0 = 8 * p2 + g;         // t = 32p2 + 4g + j
            const int tg1 = 8 * p2 + 4 + g;     // t = 32p2 + 16 + 4g + j
#pragma unroll
            for (int cc = 0; cc < 2; ++cc) {
                bf16x4 a0 = *(const bf16x4*)&Vs[(tg0 * 32 + ((cc * 16 + c) ^ (tg0 & 7))) * 4];
                bf16x4 a1 = *(const bf16x4*)&Vs[(tg1 * 32 + ((cc * 16 + c) ^ (tg1 & 7))) * 4];
                bf16x8 av = {a0[0], a0[1], a0[2], a0[3], a1[0], a1[1], a1[2], a1[3]};
                o[cc] = mfma32(av, pb, o[cc]);
            }
        }
        __builtin_amdgcn_s_setprio(0);

        // normalize + gate + store: ONE 16B store in permuted layout
        bf16x8 ov8;
#pragma unroll
        for (int cc = 0; cc < 2; ++cc)
#pragma unroll
            for (int j = 0; j < 4; ++j)
                ov8[cc * 4 + j] = (bf16)(o[cc][j] * rinv * (float)gv8[cc * 4 + j]);
        *(bf16x8*)(Oh + (size_t)q * 32 + g * 8) = ov8;
    }
}

// ---------------- output projection (R19 verbatim) --------------------------
// Og: [8][M][perm] bf16 ; woT: [128][256] bf16 (k permuted identically) ;
// out: [M][128] fp32.  Shared k-permutation cancels in the dot product.
__global__ __launch_bounds__(256, 4)
void out_proj_kernel(const bf16* __restrict__ Og, const bf16* __restrict__ woT,
                     const float* __restrict__ bo, float* __restrict__ out)
{
    const int tid = threadIdx.x;
    const int lane = tid & 63, w = tid >> 6;
    const int c = lane & 15, g = lane >> 4;
    const int mbase = blockIdx.x * 64;
    const int mstrip = mbase + (w >> 1) * 32;
    const int nstrip = (w & 1) * 64;
    const f32x4 fzero = {0.f, 0.f, 0.f, 0.f};

    f32x4 acc[2][4];
#pragma unroll
    for (int a = 0; a < 2; ++a)
#pragma unroll
        for (int b = 0; b < 4; ++b) acc[a][b] = fzero;

#pragma unroll
    for (int kk = 0; kk < 8; ++kk) {              // kk = head
        bf16x8 af[2], bfr[4];
#pragma unroll
        for (int mi = 0; mi < 2; ++mi)
            af[mi] = *(const bf16x8*)(Og + ((size_t)kk * M_TOT + mstrip + mi * 16 + c) * 32 + g * 8);
#pragma unroll
        for (int ni = 0; ni < 4; ++ni)
            bfr[ni] = *(const bf16x8*)(woT + (size_t)(nstrip + ni * 16 + c) * 256 + kk * 32 + g * 8);
#pragma unroll
        for (int mi = 0; mi < 2; ++mi)
#pragma unroll
            for (int ni = 0; ni < 4; ++ni)
                acc[mi][ni] = mfma32(af[mi], bfr[ni], acc[mi][ni]);
    }

#pragma unroll
    for (int mi = 0; mi < 2; ++mi)
#pragma unroll
        for (int ni = 0; ni < 4; ++ni) {
            int n = nstrip + ni * 16 + c;
            float bias = bo[n];
#pragma unroll
            for (int j = 0; j < 4; ++j) {
                int m = mstrip + mi * 16 + g * 4 + j;
                out[(size_t)m * 128 + n] = acc[mi][ni][j] + bias;
            }
        }
}

// ---------------------------------------------------------------------------
extern "C" void kernel_launch(void* const* d_in, const int* in_sizes, int n_in,
                              void* d_out, int out_size, void* d_ws, size_t ws_size,
                              hipStream_t stream)
{
    const float* q_x       = (const float*)d_in[0];
    const float* kv_x      = (const float*)d_in[1];
    const float* bias_mask = (const float*)d_in[2];
    const float* bias_pair = (const float*)d_in[3];
    const float* wq        = (const float*)d_in[4];
    const float* wk        = (const float*)d_in[5];
    const float* wv        = (const float*)d_in[6];
    const float* wg        = (const float*)d_in[7];
    const float* bg        = (const float*)d_in[8];
    const float* wo        = (const float*)d_in[9];
    const float* bo        = (const float*)d_in[10];
    float* out = (float*)d_out;

    char* ws = (char*)d_ws;
    const size_t MB = 1024ull * 1024ull;
    bf16*  Qb  = (bf16*)(ws);                    // [8][65536][32]
    bf16*  Kb  = (bf16*)(ws + 32 * MB);          // K images [2048][8192]
    bf16*  Gb  = (bf16*)(ws + 64 * MB);          // [8][65536][perm]
    bf16*  Vtb = (bf16*)(ws + 96 * MB);          // V images [2048][8192]
    bf16*  Ogb = (bf16*)(ws + 128 * MB);         // [8][65536][perm]
    bf16*  Wt  = (bf16*)(ws + 160 * MB);         // 5 x 32768 bf16 (320 KB)
    bf16*  bpb = (bf16*)(ws + 160 * MB + 512 * 1024);    // [8][256][256] bf16
    float* bms = (float*)(ws + 160 * MB + 2560 * 1024);  // [256][256] f32

    wprep_kernel<<<dim3(128, 7), 256, 0, stream>>>(wq, wk, wv, wg, wo, Wt,
                                                   bias_pair, bpb, bias_mask, bms);

    // Q + G + K image + V image in ONE launch (template-specialized paths)
    proj_all_kernel<<<dim3(512, 2), 512, 0, stream>>>(q_x, kv_x, Wt, bg,
                                                      Qb, Gb, Kb, Vtb);

    attn_kernel<<<dim3(8, 256), 256, 0, stream>>>(Qb, Kb, Vtb, Gb, bms, bpb, Ogb);

    out_proj_kernel<<<dim3(1024), 256, 0, stream>>>(Ogb, Wt + 4 * 32768, bo, out);
}